// Round 1
// baseline (1071.514 us; speedup 1.0000x reference)
//
#include <hip/hip_runtime.h>

typedef __bf16 bf16_t;
typedef __bf16 bf16x8 __attribute__((ext_vector_type(8)));
typedef float floatx4 __attribute__((ext_vector_type(4)));

// ---------------------------------------------------------------------------
// k1: x (f32) -> bf16
__global__ __launch_bounds__(256) void cvt_x(const float* __restrict__ x,
                                             bf16_t* __restrict__ xb) {
    int i = (blockIdx.x * 256 + threadIdx.x) * 4;
    float4 v = *(const float4*)&x[i];
    bf16_t* o = &xb[i];
    o[0] = (bf16_t)v.x; o[1] = (bf16_t)v.y; o[2] = (bf16_t)v.z; o[3] = (bf16_t)v.w;
}

// k2: weight [NH, D, H] f32 -> w_t [n*64+h][d] bf16   (NH=16, D=1024, H=64)
__global__ __launch_bounds__(256) void prep_w(const float* __restrict__ w,
                                              bf16_t* __restrict__ wt) {
    int o = blockIdx.x * 256 + threadIdx.x;      // over 1048576
    int d = o & 1023, nh = o >> 10;
    int n = nh >> 6, h = nh & 63;
    wt[o] = (bf16_t)w[(size_t)n * 65536 + (size_t)d * 64 + h];
}

// k3: lin_w [D][NH*H] f32 -> bf16 (already B^T layout for proj GEMM)
__global__ __launch_bounds__(256) void cvt_linw(const float* __restrict__ lw,
                                                bf16_t* __restrict__ lb) {
    int i = (blockIdx.x * 256 + threadIdx.x) * 4;
    float4 v = *(const float4*)&lw[i];
    bf16_t* o = &lb[i];
    o[0] = (bf16_t)v.x; o[1] = (bf16_t)v.y; o[2] = (bf16_t)v.z; o[3] = (bf16_t)v.w;
}

// ---------------------------------------------------------------------------
// Shared GEMM for stage A (logits) and stage D (output proj).
// C[8192,1024] = A[8192,1024] @ Bt[1024,1024]^T, 128x128 tile, 4 waves (2x2).
// mode 0: out_bf[idx] = bf16(acc)
// mode 1: out_f[idx] = acc + bias[col] + xres[idx]
__global__ __launch_bounds__(256) void gemm_ad(const bf16_t* __restrict__ A,
                                               const bf16_t* __restrict__ Bt,
                                               int mode,
                                               bf16_t* __restrict__ out_bf,
                                               float* __restrict__ out_f,
                                               const float* __restrict__ bias,
                                               const float* __restrict__ xres) {
    __shared__ __attribute__((aligned(16))) bf16_t As[128][40];
    __shared__ __attribute__((aligned(16))) bf16_t Bs[128][40];
    int tid = threadIdx.x;
    int bm = blockIdx.x * 128, bn = blockIdx.y * 128;
    int wave = tid >> 6, lane = tid & 63;
    int wm = (wave >> 1) * 64, wn = (wave & 1) * 64;
    int l15 = lane & 15, quad = lane >> 4;
    floatx4 acc[4][4] = {};
    const bf16_t* abase = A + (size_t)bm * 1024;
    const bf16_t* bbase = Bt + (size_t)bn * 1024;
    for (int kt = 0; kt < 1024; kt += 32) {
        __syncthreads();
        for (int i = 0; i < 2; i++) {
            int c = tid + i * 256;
            int r = c >> 2, c8 = (c & 3) * 8;
            *(bf16x8*)&As[r][c8] = *(const bf16x8*)&abase[(size_t)r * 1024 + kt + c8];
            *(bf16x8*)&Bs[r][c8] = *(const bf16x8*)&bbase[(size_t)r * 1024 + kt + c8];
        }
        __syncthreads();
        bf16x8 af[4], bfr[4];
        for (int mi = 0; mi < 4; mi++) af[mi] = *(const bf16x8*)&As[wm + mi * 16 + l15][quad * 8];
        for (int ni = 0; ni < 4; ni++) bfr[ni] = *(const bf16x8*)&Bs[wn + ni * 16 + l15][quad * 8];
        for (int mi = 0; mi < 4; mi++)
            for (int ni = 0; ni < 4; ni++)
                acc[mi][ni] = __builtin_amdgcn_mfma_f32_16x16x32_bf16(af[mi], bfr[ni], acc[mi][ni], 0, 0, 0);
    }
    for (int mi = 0; mi < 4; mi++)
        for (int ni = 0; ni < 4; ni++) {
            int col = bn + wn + ni * 16 + l15;
            for (int r = 0; r < 4; r++) {
                int row = bm + wm + mi * 16 + quad * 4 + r;
                size_t idx = (size_t)row * 1024 + col;
                float v = acc[mi][ni][r];
                if (mode == 0) out_bf[idx] = (bf16_t)v;
                else           out_f[idx] = v + bias[col] + xres[idx];
            }
        }
}

// ---------------------------------------------------------------------------
// k5: logits [b*1024+s][n*64+h] -> vt [(n*8+b)*64+h][s]  (V^T per head)
__global__ __launch_bounds__(256) void transpose_v(const bf16_t* __restrict__ logits,
                                                   bf16_t* __restrict__ vt) {
    __shared__ __attribute__((aligned(16))) bf16_t T[64][72];
    int nb = blockIdx.y;
    int n = nb >> 3, b = nb & 7;
    int s0 = blockIdx.x * 64;
    int tid = threadIdx.x;
    const bf16_t* src = logits + (size_t)(b * 1024 + s0) * 1024 + n * 64;
    for (int i = 0; i < 2; i++) {
        int c = tid + i * 256;
        int r = c >> 3, c8 = (c & 7) * 8;
        *(bf16x8*)&T[r][c8] = *(const bf16x8*)&src[(size_t)r * 1024 + c8];
    }
    __syncthreads();
    bf16_t* dst = vt + (size_t)nb * 64 * 1024 + s0;
    for (int i = 0; i < 2; i++) {
        int c = tid + i * 256;
        int h = c >> 3, sx = (c & 7) * 8;
        bf16x8 o;
        for (int j = 0; j < 8; j++) o[j] = T[sx + j][h];
        *(bf16x8*)&dst[(size_t)h * 1024 + sx] = o;
    }
}

// ---------------------------------------------------------------------------
// k6: raw scaled scores -> d_out attn region.  Per (n,b): S = (Q @ Q^T)/8.
// grid: x = row-tile (16), y = col-tile (4), z = nb (128). WG tile 64x256.
__global__ __launch_bounds__(256) void scores_kernel(const bf16_t* __restrict__ logits,
                                                     float* __restrict__ attn) {
    __shared__ __attribute__((aligned(16))) bf16_t Qs[64][72];
    __shared__ __attribute__((aligned(16))) bf16_t Ks[256][72];
    int nb = blockIdx.z;
    int n = nb >> 3, b = nb & 7;
    int r0 = blockIdx.x * 64;
    int t0 = blockIdx.y * 256;
    int tid = threadIdx.x;
    const bf16_t* qbase = logits + (size_t)(b * 1024 + r0) * 1024 + n * 64;
    const bf16_t* kbase = logits + (size_t)(b * 1024 + t0) * 1024 + n * 64;
    for (int i = 0; i < 2; i++) {
        int c = tid + i * 256;
        int r = c >> 3, c8 = (c & 7) * 8;
        *(bf16x8*)&Qs[r][c8] = *(const bf16x8*)&qbase[(size_t)r * 1024 + c8];
    }
    for (int i = 0; i < 8; i++) {
        int c = tid + i * 256;
        int r = c >> 3, c8 = (c & 7) * 8;
        *(bf16x8*)&Ks[r][c8] = *(const bf16x8*)&kbase[(size_t)r * 1024 + c8];
    }
    __syncthreads();
    int wave = tid >> 6, lane = tid & 63;
    int wn = wave * 64;
    int l15 = lane & 15, quad = lane >> 4;
    floatx4 acc[4][4] = {};
    for (int ks = 0; ks < 2; ks++) {
        bf16x8 af[4], bfr[4];
        for (int mi = 0; mi < 4; mi++) af[mi] = *(const bf16x8*)&Qs[mi * 16 + l15][ks * 32 + quad * 8];
        for (int ni = 0; ni < 4; ni++) bfr[ni] = *(const bf16x8*)&Ks[wn + ni * 16 + l15][ks * 32 + quad * 8];
        for (int mi = 0; mi < 4; mi++)
            for (int ni = 0; ni < 4; ni++)
                acc[mi][ni] = __builtin_amdgcn_mfma_f32_16x16x32_bf16(af[mi], bfr[ni], acc[mi][ni], 0, 0, 0);
    }
    float* obase = attn + (size_t)nb * 1024 * 1024;
    for (int mi = 0; mi < 4; mi++)
        for (int ni = 0; ni < 4; ni++) {
            int t = t0 + wn + ni * 16 + l15;
            for (int r = 0; r < 4; r++) {
                int s = r0 + mi * 16 + quad * 4 + r;
                obase[(size_t)s * 1024 + t] = acc[mi][ni][r] * 0.125f;
            }
        }
}

// ---------------------------------------------------------------------------
// k7: in-place softmax over each 1024-wide row of attn. grid = 131072 rows.
__global__ __launch_bounds__(256) void softmax_kernel(float* __restrict__ attn) {
    size_t row = blockIdx.x;
    float* p = attn + row * 1024;
    int tid = threadIdx.x;
    float4 v = *(const float4*)&p[tid * 4];
    float m = fmaxf(fmaxf(v.x, v.y), fmaxf(v.z, v.w));
    for (int off = 32; off; off >>= 1) m = fmaxf(m, __shfl_xor(m, off));
    __shared__ float red[4], red2[4];
    int wave = tid >> 6;
    if ((tid & 63) == 0) red[wave] = m;
    __syncthreads();
    m = fmaxf(fmaxf(red[0], red[1]), fmaxf(red[2], red[3]));
    v.x = __expf(v.x - m); v.y = __expf(v.y - m);
    v.z = __expf(v.z - m); v.w = __expf(v.w - m);
    float s = v.x + v.y + v.z + v.w;
    for (int off = 32; off; off >>= 1) s += __shfl_xor(s, off);
    if ((tid & 63) == 0) red2[wave] = s;
    __syncthreads();
    s = red2[0] + red2[1] + red2[2] + red2[3];
    float inv = 1.0f / s;
    v.x *= inv; v.y *= inv; v.z *= inv; v.w *= inv;
    *(float4*)&p[tid * 4] = v;
}

// ---------------------------------------------------------------------------
// k8: out_heads = attn @ V.  Per nb: [1024x1024]@[1024x64].
// grid: x = row-tile (8, 128 rows each), y = nb (128). Wave tile 32x64.
__global__ __launch_bounds__(256) void av_kernel(const float* __restrict__ attn,
                                                 const bf16_t* __restrict__ vt,
                                                 bf16_t* __restrict__ outh) {
    __shared__ __attribute__((aligned(16))) bf16_t As[128][40];
    __shared__ __attribute__((aligned(16))) bf16_t Bs[64][40];
    int nb = blockIdx.y;
    int n = nb >> 3, b = nb & 7;
    int m0 = blockIdx.x * 128;
    int tid = threadIdx.x;
    int wave = tid >> 6, lane = tid & 63;
    int wm = wave * 32;
    int l15 = lane & 15, quad = lane >> 4;
    const float* abase = attn + (size_t)nb * 1024 * 1024 + (size_t)m0 * 1024;
    const bf16_t* vbase = vt + (size_t)nb * 64 * 1024;
    floatx4 acc[2][4] = {};
    for (int kt = 0; kt < 1024; kt += 32) {
        __syncthreads();
        for (int i = 0; i < 4; i++) {
            int c = tid + i * 256;
            int r = c >> 3, c4 = (c & 7) * 4;
            float4 v = *(const float4*)&abase[(size_t)r * 1024 + kt + c4];
            bf16_t* dst = &As[r][c4];
            dst[0] = (bf16_t)v.x; dst[1] = (bf16_t)v.y; dst[2] = (bf16_t)v.z; dst[3] = (bf16_t)v.w;
        }
        {
            int r = tid >> 2, c8 = (tid & 3) * 8;
            *(bf16x8*)&Bs[r][c8] = *(const bf16x8*)&vbase[(size_t)r * 1024 + kt + c8];
        }
        __syncthreads();
        bf16x8 af[2], bfr[4];
        for (int mi = 0; mi < 2; mi++) af[mi] = *(const bf16x8*)&As[wm + mi * 16 + l15][quad * 8];
        for (int ni = 0; ni < 4; ni++) bfr[ni] = *(const bf16x8*)&Bs[ni * 16 + l15][quad * 8];
        for (int mi = 0; mi < 2; mi++)
            for (int ni = 0; ni < 4; ni++)
                acc[mi][ni] = __builtin_amdgcn_mfma_f32_16x16x32_bf16(af[mi], bfr[ni], acc[mi][ni], 0, 0, 0);
    }
    for (int mi = 0; mi < 2; mi++)
        for (int ni = 0; ni < 4; ni++) {
            int h = ni * 16 + l15;
            for (int r = 0; r < 4; r++) {
                int s = m0 + wm + mi * 16 + quad * 4 + r;
                outh[(size_t)(b * 1024 + s) * 1024 + n * 64 + h] = (bf16_t)acc[mi][ni][r];
            }
        }
}

// ---------------------------------------------------------------------------
// k10: LayerNorm over D=1024. grid = 8192 rows.
__global__ __launch_bounds__(256) void ln_kernel(const float* __restrict__ z,
                                                 const float* __restrict__ g,
                                                 const float* __restrict__ beta,
                                                 float* __restrict__ y) {
    size_t row = blockIdx.x;
    const float* p = z + row * 1024;
    int tid = threadIdx.x;
    float4 v = *(const float4*)&p[tid * 4];
    float s1 = v.x + v.y + v.z + v.w;
    float s2 = v.x * v.x + v.y * v.y + v.z * v.z + v.w * v.w;
    for (int off = 32; off; off >>= 1) {
        s1 += __shfl_xor(s1, off);
        s2 += __shfl_xor(s2, off);
    }
    __shared__ float r1[4], r2[4];
    int wave = tid >> 6;
    if ((tid & 63) == 0) { r1[wave] = s1; r2[wave] = s2; }
    __syncthreads();
    s1 = r1[0] + r1[1] + r1[2] + r1[3];
    s2 = r2[0] + r2[1] + r2[2] + r2[3];
    float mu = s1 * (1.0f / 1024.0f);
    float var = s2 * (1.0f / 1024.0f) - mu * mu;
    float rstd = rsqrtf(var + 1e-5f);
    float4 gv = *(const float4*)&g[tid * 4];
    float4 bv = *(const float4*)&beta[tid * 4];
    float4 o;
    o.x = (v.x - mu) * rstd * gv.x + bv.x;
    o.y = (v.y - mu) * rstd * gv.y + bv.y;
    o.z = (v.z - mu) * rstd * gv.z + bv.z;
    o.w = (v.w - mu) * rstd * gv.w + bv.w;
    *(float4*)&y[row * 1024 + tid * 4] = o;
}

// ---------------------------------------------------------------------------
extern "C" void kernel_launch(void* const* d_in, const int* in_sizes, int n_in,
                              void* d_out, int out_size, void* d_ws, size_t ws_size,
                              hipStream_t stream) {
    const float* x     = (const float*)d_in[0];  // [8,1024,1024]
    const float* w     = (const float*)d_in[1];  // [16,1024,64]
    const float* lw    = (const float*)d_in[2];  // [1024,1024]
    const float* lb    = (const float*)d_in[3];  // [1024]
    const float* lg    = (const float*)d_in[4];  // [1024]
    const float* lbeta = (const float*)d_in[5];  // [1024]
    float* y    = (float*)d_out;                 // [8,1024,1024]
    float* attn = y + 8388608;                   // [128,1024,1024]

    // Workspace overlay (54.5 MB total):
    //   [0,16M)     xb (stage A input)   -> reused as outh (stage C output)
    //   [16M,18M)   w_t
    //   [18M,20M)   lin_w bf16
    //   [20M,37M)   logits bf16          -> reused as lower half of z
    //   [37M,53M)   vt                   -> reused as upper half of z
    char* ws = (char*)d_ws;
    bf16_t* xb     = (bf16_t*)(ws);
    bf16_t* outh   = (bf16_t*)(ws);
    bf16_t* wt     = (bf16_t*)(ws + 16777216);
    bf16_t* lwb    = (bf16_t*)(ws + 18874368);
    bf16_t* logits = (bf16_t*)(ws + 20971520);
    float*  z      = (float*)(ws + 20971520);
    bf16_t* vt     = (bf16_t*)(ws + 37748736);

    hipLaunchKernelGGL(cvt_x,        dim3(8192),       dim3(256), 0, stream, x, xb);
    hipLaunchKernelGGL(prep_w,       dim3(4096),       dim3(256), 0, stream, w, wt);
    hipLaunchKernelGGL(cvt_linw,     dim3(1024),       dim3(256), 0, stream, lw, lwb);
    hipLaunchKernelGGL(gemm_ad,      dim3(64, 8),      dim3(256), 0, stream,
                       xb, wt, 0, logits, (float*)nullptr, (const float*)nullptr, (const float*)nullptr);
    hipLaunchKernelGGL(transpose_v,  dim3(16, 128),    dim3(256), 0, stream, logits, vt);
    hipLaunchKernelGGL(scores_kernel,dim3(16, 4, 128), dim3(256), 0, stream, logits, attn);
    hipLaunchKernelGGL(softmax_kernel, dim3(131072),   dim3(256), 0, stream, attn);
    hipLaunchKernelGGL(av_kernel,    dim3(8, 128),     dim3(256), 0, stream, attn, vt, outh);
    hipLaunchKernelGGL(gemm_ad,      dim3(64, 8),      dim3(256), 0, stream,
                       outh, lwb, 1, (bf16_t*)nullptr, z, lb, x);
    hipLaunchKernelGGL(ln_kernel,    dim3(8192),       dim3(256), 0, stream, z, lg, lbeta, y);
}